// Round 1
// baseline (1022.775 us; speedup 1.0000x reference)
//
#include <hip/hip_runtime.h>
#include <cstdint>

typedef unsigned long long u64;
typedef unsigned int u32;

#define CLS_T   0.05f
#define TOPK    300
#define NWORDS  5          // ceil(300/64)
#define CAND_CAP 1024
#define HBINS   2560
#define KEY_BASE 0x3D000000u

// ---------------- decode boxes (+clip) ----------------
__global__ void decode_kernel(const float* __restrict__ anc,
                              const float* __restrict__ reg,
                              const int* __restrict__ ph,
                              const int* __restrict__ pw,
                              float* __restrict__ boxes, int A)
{
    int a = blockIdx.x * blockDim.x + threadIdx.x;
    if (a >= A) return;
    float x1 = anc[a*4+0], y1 = anc[a*4+1], x2 = anc[a*4+2], y2 = anc[a*4+3];
    float w = x2 - x1, h = y2 - y1;
    float cx = x1 + 0.5f*w, cy = y1 + 0.5f*h;
    float r0 = reg[a*4+0]*0.1f, r1 = reg[a*4+1]*0.1f;
    float r2 = reg[a*4+2]*0.2f, r3 = reg[a*4+3]*0.2f;
    float pcx = cx + r0*w, pcy = cy + r1*h;
    float pw_ = expf(r2)*w, ph_ = expf(r3)*h;
    float W = (float)(*pw), H = (float)(*ph);
    float bx1 = fmaxf(pcx - 0.5f*pw_, 0.0f);
    float by1 = fmaxf(pcy - 0.5f*ph_, 0.0f);
    float bx2 = fminf(pcx + 0.5f*pw_, W);
    float by2 = fminf(pcy + 0.5f*ph_, H);
    boxes[a*4+0] = bx1; boxes[a*4+1] = by1;
    boxes[a*4+2] = bx2; boxes[a*4+3] = by2;
}

// ---------------- per-class top-K + NMS ----------------
__global__ __launch_bounds__(256) void topk_nms_kernel(
    const float* __restrict__ cls,
    const float* __restrict__ boxes,
    u64* __restrict__ akey,
    int A, int C)
{
    const int c   = blockIdx.x;
    const int tid = threadIdx.x;

    __shared__ u32 hist[HBINS];
    __shared__ u64 cand[CAND_CAP];
    __shared__ float bx1[TOPK], by1[TOPK], bx2[TOPK], by2[TOPK], bar[TOPK];
    __shared__ u64 iomask[TOPK][NWORDS];
    __shared__ u64 keepm[NWORDS];
    __shared__ u32 s_sel1, s_sel2, s_rem, s_cnt;

    // ----- level-1 histogram: bins of 16384 ulps over k = bits - KEY_BASE
    for (int i = tid; i < HBINS; i += 256) hist[i] = 0;
    __syncthreads();
    for (int a = tid; a < A; a += 256) {
        float s = cls[(size_t)a * C + c];
        if (s > CLS_T) {
            u32 k = __float_as_uint(s) - KEY_BASE;
            u32 b = k >> 14; if (b >= HBINS) b = HBINS - 1;
            atomicAdd(&hist[b], 1u);
        }
    }
    __syncthreads();
    if (tid == 0) {
        u32 cum = 0; int sel = 0;
        for (int d = HBINS - 1; d >= 0; --d) {
            u32 nc = cum + hist[d];
            if (nc >= TOPK) { sel = d; break; }
            cum = nc;
        }
        s_sel1 = (u32)sel;
        s_rem  = TOPK - cum;      // >=1 always
    }
    __syncthreads();
    const u32 sel1 = s_sel1;

    // ----- level-2 histogram: 256 bins of 64 ulps inside bin sel1
    for (int i = tid; i < 256; i += 256) hist[i] = 0;
    __syncthreads();
    for (int a = tid; a < A; a += 256) {
        float s = cls[(size_t)a * C + c];
        if (s > CLS_T) {
            u32 k = __float_as_uint(s) - KEY_BASE;
            u32 b = k >> 14; if (b >= HBINS) b = HBINS - 1;
            if (b == sel1) atomicAdd(&hist[(k >> 6) & 0xFF], 1u);
        }
    }
    __syncthreads();
    if (tid == 0) {
        u32 rem = s_rem, cum = 0; int sel = 0;
        for (int d = 255; d >= 0; --d) {
            u32 nc = cum + hist[d];
            if (nc >= rem) { sel = d; break; }
            cum = nc;
        }
        s_sel2 = (u32)sel;
        s_cnt  = 0;
    }
    __syncthreads();
    const u32 thresh = (sel1 << 14) | (s_sel2 << 6);

    // ----- collect candidates: key' >= thresh
    for (int a = tid; a < A; a += 256) {
        float s = cls[(size_t)a * C + c];
        if (s > CLS_T) {
            u32 bits = __float_as_uint(s);
            u32 k = bits - KEY_BASE;
            if (k >= thresh) {
                u32 pos = atomicAdd(&s_cnt, 1u);
                if (pos < CAND_CAP)
                    cand[pos] = ((u64)bits << 32) | (u32)(~(u32)a);
            }
        }
    }
    __syncthreads();
    const u32 total = s_cnt < CAND_CAP ? s_cnt : CAND_CAP;
    for (int i = tid; i < CAND_CAP; i += 256)
        if (i >= (int)total) cand[i] = 0;
    __syncthreads();

    // ----- bitonic sort descending (score desc, index asc via ~idx)
    for (u32 kk = 2; kk <= CAND_CAP; kk <<= 1) {
        for (u32 j = kk >> 1; j > 0; j >>= 1) {
            for (u32 i = tid; i < CAND_CAP; i += 256) {
                u32 l = i ^ j;
                if (l > i) {
                    u64 av = cand[i], bv = cand[l];
                    bool up = ((i & kk) == 0);
                    if ((up && av < bv) || (!up && av > bv)) {
                        cand[i] = bv; cand[l] = av;
                    }
                }
            }
            __syncthreads();
        }
    }
    const int T = (int)(total < TOPK ? total : TOPK);

    // ----- load candidate boxes into shared
    for (int i = tid; i < T; i += 256) {
        u32 a = ~(u32)(cand[i] & 0xFFFFFFFFull);
        float x1 = boxes[(size_t)a*4+0], y1 = boxes[(size_t)a*4+1];
        float x2 = boxes[(size_t)a*4+2], y2 = boxes[(size_t)a*4+3];
        bx1[i] = x1; by1[i] = y1; bx2[i] = x2; by2[i] = y2;
        bar[i] = fmaxf(x2 - x1, 0.0f) * fmaxf(y2 - y1, 0.0f);
    }
    __syncthreads();

    // ----- pairwise IoU masks (row i: bits j>i with iou>0.5)
    for (int i = tid; i < T; i += 256) {
        u64 m[NWORDS] = {0,0,0,0,0};
        float x1 = bx1[i], y1 = by1[i], x2 = bx2[i], y2 = by2[i], ai = bar[i];
        for (int j = i + 1; j < T; ++j) {
            float iw = fminf(x2, bx2[j]) - fmaxf(x1, bx1[j]);
            iw = fmaxf(iw, 0.0f);
            float ih = fminf(y2, by2[j]) - fmaxf(y1, by1[j]);
            ih = fmaxf(ih, 0.0f);
            float inter = iw * ih;
            float uni = ((ai + bar[j]) - inter) + 1e-8f;
            float iou = inter / uni;
            if (iou > 0.5f) m[j >> 6] |= 1ull << (j & 63);
        }
        for (int k2 = 0; k2 < NWORDS; ++k2) iomask[i][k2] = m[k2];
    }
    __syncthreads();

    // ----- serial greedy suppression via bitmask OR
    if (tid == 0) {
        u64 sup[NWORDS] = {0,0,0,0,0};
        u64 kp [NWORDS] = {0,0,0,0,0};
        for (int i = 0; i < T; ++i) {
            if (!((sup[i >> 6] >> (i & 63)) & 1ull)) {
                kp[i >> 6] |= 1ull << (i & 63);
                for (int k2 = 0; k2 < NWORDS; ++k2) sup[k2] |= iomask[i][k2];
            }
        }
        for (int k2 = 0; k2 < NWORDS; ++k2) keepm[k2] = kp[k2];
    }
    __syncthreads();

    // ----- scatter kept candidates: per-anchor max via u64 atomicMax
    for (int i = tid; i < T; i += 256) {
        if ((keepm[i >> 6] >> (i & 63)) & 1ull) {
            u64 key = cand[i];
            u32 a = ~(u32)(key & 0xFFFFFFFFull);
            u32 sbits = (u32)(key >> 32);
            u64 outk = ((u64)sbits << 32) | (u32)(255 - c);  // smaller class wins ties
            atomicMax(&akey[a], outk);
        }
    }
}

// ---------------- finalize ----------------
__global__ void finalize_kernel(const u64* __restrict__ akey,
                                float* __restrict__ out, int A)
{
    int a = blockIdx.x * blockDim.x + threadIdx.x;
    if (a >= A) return;
    float* scores = out;
    float* labels = out + A;
    float* boxes  = out + (size_t)2 * A;
    u64 k = akey[a];
    if (k) {
        scores[a] = __uint_as_float((u32)(k >> 32));
        labels[a] = (float)(int)(255u - (u32)(k & 0xFFFFFFFFull));
        // boxes already hold decoded values
    } else {
        scores[a] = 0.0f;
        labels[a] = -1.0f;
        boxes[(size_t)a*4+0] = 0.0f;
        boxes[(size_t)a*4+1] = 0.0f;
        boxes[(size_t)a*4+2] = 0.0f;
        boxes[(size_t)a*4+3] = 0.0f;
    }
}

extern "C" void kernel_launch(void* const* d_in, const int* in_sizes, int n_in,
                              void* d_out, int out_size, void* d_ws, size_t ws_size,
                              hipStream_t stream) {
    const float* cls = (const float*)d_in[0];
    const float* reg = (const float*)d_in[1];
    const float* anc = (const float*)d_in[2];
    const int*   ph  = (const int*)d_in[3];
    const int*   pw  = (const int*)d_in[4];

    int A = in_sizes[2] / 4;
    int C = in_sizes[0] / A;

    float* out       = (float*)d_out;
    float* out_boxes = out + (size_t)2 * A;
    u64*   akey      = (u64*)d_ws;

    hipMemsetAsync(d_ws, 0, (size_t)A * sizeof(u64), stream);

    decode_kernel<<<(A + 255) / 256, 256, 0, stream>>>(anc, reg, ph, pw, out_boxes, A);
    topk_nms_kernel<<<C, 256, 0, stream>>>(cls, out_boxes, akey, A, C);
    finalize_kernel<<<(A + 255) / 256, 256, 0, stream>>>(akey, out, A);
}

// Round 2
// 198.689 us; speedup vs baseline: 5.1476x; 5.1476x over previous
//
#include <hip/hip_runtime.h>
#include <cstdint>

typedef unsigned long long u64;
typedef unsigned int u32;

#define CLS_T    0.05f
#define TOPK     300
#define NWORDS   5          // ceil(300/64)
#define CAP2     2048
#define HBINS    2560
#define KEY_BASE 0x3D000000u
#define NT       1024
#define TA       64         // anchors per transpose tile

// ---------------- decode boxes (+clip) ----------------
__global__ void decode_kernel(const float* __restrict__ anc,
                              const float* __restrict__ reg,
                              const int* __restrict__ ph,
                              const int* __restrict__ pw,
                              float* __restrict__ boxes, int A)
{
    int a = blockIdx.x * blockDim.x + threadIdx.x;
    if (a >= A) return;
    float x1 = anc[a*4+0], y1 = anc[a*4+1], x2 = anc[a*4+2], y2 = anc[a*4+3];
    float w = x2 - x1, h = y2 - y1;
    float cx = x1 + 0.5f*w, cy = y1 + 0.5f*h;
    float r0 = reg[a*4+0]*0.1f, r1 = reg[a*4+1]*0.1f;
    float r2 = reg[a*4+2]*0.2f, r3 = reg[a*4+3]*0.2f;
    float pcx = cx + r0*w, pcy = cy + r1*h;
    float pw_ = expf(r2)*w, ph_ = expf(r3)*h;
    float W = (float)(*pw), H = (float)(*ph);
    boxes[a*4+0] = fmaxf(pcx - 0.5f*pw_, 0.0f);
    boxes[a*4+1] = fmaxf(pcy - 0.5f*ph_, 0.0f);
    boxes[a*4+2] = fminf(pcx + 0.5f*pw_, W);
    boxes[a*4+3] = fminf(pcy + 0.5f*ph_, H);
}

// ---------------- transpose cls[A][80] -> clsT[80][A] ----------------
__global__ __launch_bounds__(256) void transpose_kernel(
    const float* __restrict__ in, float* __restrict__ out, int A)
{
    const int C = 80;
    __shared__ float tile[TA * 81];   // pad 80->81: conflict-free strided reads
    int a0 = blockIdx.x * TA;
    int rows = A - a0; if (rows > TA) rows = TA;

    if (rows == TA) {
        // contiguous 64*80 floats
        const float4* in4 = (const float4*)(in + (size_t)a0 * C);
        for (int w = threadIdx.x; w < TA * C / 4; w += 256) {
            float4 v = in4[w];
            int l = w * 4; int r = l / C; int c = l - r * C;
            float* p = &tile[r * 81 + c];
            p[0] = v.x; p[1] = v.y; p[2] = v.z; p[3] = v.w;
        }
    } else {
        for (int l = threadIdx.x; l < rows * C; l += 256) {
            int r = l / C; int c = l - r * C;
            tile[r * 81 + c] = in[(size_t)(a0 + r) * C + c];
        }
    }
    __syncthreads();
    // store: each wave writes 64 consecutive anchors of one class (256 B)
    for (int m = threadIdx.x; m < C * TA; m += 256) {
        int c = m >> 6; int r = m & 63;
        if (r < rows)
            out[(size_t)c * A + a0 + r] = tile[r * 81 + c];
    }
}

// ---------------- per-class top-K + NMS ----------------
__global__ __launch_bounds__(NT) void topk_nms_kernel(
    const float* __restrict__ clsT,   // [C][A] (may be null)
    const float* __restrict__ cls,    // [A][C] fallback
    const float* __restrict__ boxes,
    u64* __restrict__ akey,
    int A, int C)
{
    const int c   = blockIdx.x;
    const int tid = threadIdx.x;

    __shared__ u32 hist[HBINS];
    __shared__ u64 cand[CAP2];
    __shared__ float bx1[TOPK], by1[TOPK], bx2[TOPK], by2[TOPK], bar[TOPK];
    __shared__ u64 iomask[TOPK][NWORDS];
    __shared__ u64 keepm[NWORDS];
    __shared__ u32 s_sel1, s_rem, s_cnt, s_thresh, s_T;

    const float* row = clsT ? (clsT + (size_t)c * A) : nullptr;

    // ===== pass 1: coarse histogram (bins of 16384 ulps) =====
    for (int i = tid; i < HBINS; i += NT) hist[i] = 0;
    __syncthreads();

    if (row) {
        const float4* r4 = (const float4*)row;
        int n4 = A >> 2, n2 = n4 >> 1;
        for (int i = tid; i < n2; i += NT) {
            float4 va = r4[i];
            float4 vb = r4[i + n2];
            float ss[8] = {va.x,va.y,va.z,va.w, vb.x,vb.y,vb.z,vb.w};
            #pragma unroll
            for (int k = 0; k < 8; ++k) {
                float s = ss[k];
                if (s > CLS_T) {
                    u32 kk = __float_as_uint(s) - KEY_BASE;
                    u32 b = kk >> 14; if (b >= HBINS) b = HBINS - 1;
                    atomicAdd(&hist[b], 1u);
                }
            }
        }
        for (int a = (n2 << 3) + tid; a < A; a += NT) {   // tail (n4 odd / A%4)
            float s = row[a];
            if (s > CLS_T) {
                u32 kk = __float_as_uint(s) - KEY_BASE;
                u32 b = kk >> 14; if (b >= HBINS) b = HBINS - 1;
                atomicAdd(&hist[b], 1u);
            }
        }
    } else {
        for (int a = tid; a < A; a += NT) {
            float s = cls[(size_t)a * C + c];
            if (s > CLS_T) {
                u32 kk = __float_as_uint(s) - KEY_BASE;
                u32 b = kk >> 14; if (b >= HBINS) b = HBINS - 1;
                atomicAdd(&hist[b], 1u);
            }
        }
    }
    __syncthreads();
    if (tid == 0) {
        u32 cum = 0; int sel = 0;
        for (int d = HBINS - 1; d >= 0; --d) {
            u32 nc = cum + hist[d];
            if (nc >= TOPK) { sel = d; break; }
            cum = nc;
        }
        s_sel1 = (u32)sel;
        s_rem  = TOPK - cum;
        s_cnt  = 0;
    }
    __syncthreads();
    const u32 sel1 = s_sel1;
    const u32 coarse_thr = sel1 << 14;

    // zero fine histogram (reuse hist[0..255])
    for (int i = tid; i < 256; i += NT) hist[i] = 0;
    __syncthreads();

    // ===== pass 2: fused fine-hist + candidate collection =====
    if (row) {
        const float4* r4 = (const float4*)row;
        int n4 = A >> 2, n2 = n4 >> 1;
        for (int i = tid; i < n2; i += NT) {
            float4 va = r4[i];
            float4 vb = r4[i + n2];
            float ss[8] = {va.x,va.y,va.z,va.w, vb.x,vb.y,vb.z,vb.w};
            u32 as[8] = {(u32)(4*i),(u32)(4*i+1),(u32)(4*i+2),(u32)(4*i+3),
                         (u32)(4*(i+n2)),(u32)(4*(i+n2)+1),(u32)(4*(i+n2)+2),(u32)(4*(i+n2)+3)};
            #pragma unroll
            for (int k = 0; k < 8; ++k) {
                float s = ss[k];
                if (s > CLS_T) {
                    u32 bits = __float_as_uint(s);
                    u32 kk = bits - KEY_BASE;
                    u32 b = kk >> 14; if (b >= HBINS) b = HBINS - 1;
                    if (b == sel1) atomicAdd(&hist[(kk >> 6) & 255], 1u);
                    if (kk >= coarse_thr) {
                        u32 pos = atomicAdd(&s_cnt, 1u);
                        if (pos < CAP2) cand[pos] = ((u64)bits << 32) | (u32)(~as[k]);
                    }
                }
            }
        }
        for (int a = (n2 << 3) + tid; a < A; a += NT) {
            float s = row[a];
            if (s > CLS_T) {
                u32 bits = __float_as_uint(s);
                u32 kk = bits - KEY_BASE;
                u32 b = kk >> 14; if (b >= HBINS) b = HBINS - 1;
                if (b == sel1) atomicAdd(&hist[(kk >> 6) & 255], 1u);
                if (kk >= coarse_thr) {
                    u32 pos = atomicAdd(&s_cnt, 1u);
                    if (pos < CAP2) cand[pos] = ((u64)bits << 32) | (u32)(~(u32)a);
                }
            }
        }
    } else {
        for (int a = tid; a < A; a += NT) {
            float s = cls[(size_t)a * C + c];
            if (s > CLS_T) {
                u32 bits = __float_as_uint(s);
                u32 kk = bits - KEY_BASE;
                u32 b = kk >> 14; if (b >= HBINS) b = HBINS - 1;
                if (b == sel1) atomicAdd(&hist[(kk >> 6) & 255], 1u);
                if (kk >= coarse_thr) {
                    u32 pos = atomicAdd(&s_cnt, 1u);
                    if (pos < CAP2) cand[pos] = ((u64)bits << 32) | (u32)(~(u32)a);
                }
            }
        }
    }
    __syncthreads();

    // ===== fine threshold =====
    if (tid == 0) {
        u32 rem = s_rem, cum = 0; int sel = 0;
        for (int d = 255; d >= 0; --d) {
            u32 nc = cum + hist[d];
            if (nc >= rem) { sel = d; break; }
            cum = nc;
        }
        s_thresh = coarse_thr | ((u32)sel << 6);
    }
    __syncthreads();
    const u32 thresh = s_thresh;

    u32 total = s_cnt;
    u32 totalc;
    if (total > CAP2) {
        // fallback: re-scan with fine threshold (uniform branch -> barriers ok)
        if (tid == 0) s_cnt = 0;
        __syncthreads();
        if (row) {
            for (int a = tid; a < A; a += NT) {
                float s = row[a];
                if (s > CLS_T) {
                    u32 bits = __float_as_uint(s);
                    u32 kk = bits - KEY_BASE;
                    if (kk >= thresh) {
                        u32 pos = atomicAdd(&s_cnt, 1u);
                        if (pos < CAP2) cand[pos] = ((u64)bits << 32) | (u32)(~(u32)a);
                    }
                }
            }
        } else {
            for (int a = tid; a < A; a += NT) {
                float s = cls[(size_t)a * C + c];
                if (s > CLS_T) {
                    u32 bits = __float_as_uint(s);
                    u32 kk = bits - KEY_BASE;
                    if (kk >= thresh) {
                        u32 pos = atomicAdd(&s_cnt, 1u);
                        if (pos < CAP2) cand[pos] = ((u64)bits << 32) | (u32)(~(u32)a);
                    }
                }
            }
        }
        __syncthreads();
        totalc = s_cnt < CAP2 ? s_cnt : CAP2;
    } else {
        totalc = total;
        // drop candidates below the fine threshold in-place
        for (int i = tid; i < (int)totalc; i += NT) {
            u32 kk = (u32)(cand[i] >> 32) - KEY_BASE;
            if (kk < thresh) cand[i] = 0;
        }
        __syncthreads();
    }

    // ===== bitonic sort descending (runtime pow2 size) =====
    u32 N = 512; while (N < totalc) N <<= 1;
    for (u32 i = totalc + tid; i < N; i += NT) cand[i] = 0;
    __syncthreads();
    for (u32 kk = 2; kk <= N; kk <<= 1) {
        for (u32 j = kk >> 1; j > 0; j >>= 1) {
            for (u32 i = tid; i < N; i += NT) {
                u32 l = i ^ j;
                if (l > i) {
                    u64 av = cand[i], bv = cand[l];
                    bool up = ((i & kk) == 0);
                    if ((up && av < bv) || (!up && av > bv)) {
                        cand[i] = bv; cand[l] = av;
                    }
                }
            }
            __syncthreads();
        }
    }

    if (tid == 0) {
        int t = 0;
        while (t < TOPK && cand[t] != 0) ++t;
        s_T = (u32)t;
    }
    __syncthreads();
    const int T = (int)s_T;

    // ===== load candidate boxes =====
    for (int i = tid; i < T; i += NT) {
        u32 a = ~(u32)(cand[i] & 0xFFFFFFFFull);
        float x1 = boxes[(size_t)a*4+0], y1 = boxes[(size_t)a*4+1];
        float x2 = boxes[(size_t)a*4+2], y2 = boxes[(size_t)a*4+3];
        bx1[i] = x1; by1[i] = y1; bx2[i] = x2; by2[i] = y2;
        bar[i] = fmaxf(x2 - x1, 0.0f) * fmaxf(y2 - y1, 0.0f);
    }
    __syncthreads();

    // ===== pairwise IoU masks =====
    for (int i = tid; i < T; i += NT) {
        u64 m[NWORDS] = {0,0,0,0,0};
        float x1 = bx1[i], y1 = by1[i], x2 = bx2[i], y2 = by2[i], ai = bar[i];
        for (int j = i + 1; j < T; ++j) {
            float iw = fmaxf(fminf(x2, bx2[j]) - fmaxf(x1, bx1[j]), 0.0f);
            float ih = fmaxf(fminf(y2, by2[j]) - fmaxf(y1, by1[j]), 0.0f);
            float inter = iw * ih;
            float uni = ((ai + bar[j]) - inter) + 1e-8f;
            if (inter / uni > 0.5f) m[j >> 6] |= 1ull << (j & 63);
        }
        for (int k2 = 0; k2 < NWORDS; ++k2) iomask[i][k2] = m[k2];
    }
    __syncthreads();

    // ===== serial greedy suppression =====
    if (tid == 0) {
        u64 sup[NWORDS] = {0,0,0,0,0};
        u64 kp [NWORDS] = {0,0,0,0,0};
        for (int i = 0; i < T; ++i) {
            if (!((sup[i >> 6] >> (i & 63)) & 1ull)) {
                kp[i >> 6] |= 1ull << (i & 63);
                for (int k2 = 0; k2 < NWORDS; ++k2) sup[k2] |= iomask[i][k2];
            }
        }
        for (int k2 = 0; k2 < NWORDS; ++k2) keepm[k2] = kp[k2];
    }
    __syncthreads();

    // ===== scatter kept: per-anchor max via u64 atomicMax =====
    for (int i = tid; i < T; i += NT) {
        if ((keepm[i >> 6] >> (i & 63)) & 1ull) {
            u64 key = cand[i];
            u32 a = ~(u32)(key & 0xFFFFFFFFull);
            u32 sbits = (u32)(key >> 32);
            u64 outk = ((u64)sbits << 32) | (u32)(255 - c);
            atomicMax(&akey[a], outk);
        }
    }
}

// ---------------- finalize ----------------
__global__ void finalize_kernel(const u64* __restrict__ akey,
                                float* __restrict__ out, int A)
{
    int a = blockIdx.x * blockDim.x + threadIdx.x;
    if (a >= A) return;
    float* scores = out;
    float* labels = out + A;
    float* boxes  = out + (size_t)2 * A;
    u64 k = akey[a];
    if (k) {
        scores[a] = __uint_as_float((u32)(k >> 32));
        labels[a] = (float)(int)(255u - (u32)(k & 0xFFFFFFFFull));
    } else {
        scores[a] = 0.0f;
        labels[a] = -1.0f;
        boxes[(size_t)a*4+0] = 0.0f;
        boxes[(size_t)a*4+1] = 0.0f;
        boxes[(size_t)a*4+2] = 0.0f;
        boxes[(size_t)a*4+3] = 0.0f;
    }
}

extern "C" void kernel_launch(void* const* d_in, const int* in_sizes, int n_in,
                              void* d_out, int out_size, void* d_ws, size_t ws_size,
                              hipStream_t stream) {
    const float* cls = (const float*)d_in[0];
    const float* reg = (const float*)d_in[1];
    const float* anc = (const float*)d_in[2];
    const int*   ph  = (const int*)d_in[3];
    const int*   pw  = (const int*)d_in[4];

    int A = in_sizes[2] / 4;
    int C = in_sizes[0] / A;

    float* out       = (float*)d_out;
    float* out_boxes = out + (size_t)2 * A;

    u64* akey = (u64*)d_ws;
    size_t akey_bytes = (size_t)A * sizeof(u64);
    size_t clsT_off   = (akey_bytes + 255) & ~(size_t)255;
    size_t need       = clsT_off + (size_t)A * C * sizeof(float);
    float* clsT = nullptr;
    if (C == 80 && ws_size >= need)
        clsT = (float*)((char*)d_ws + clsT_off);

    hipMemsetAsync(d_ws, 0, akey_bytes, stream);

    decode_kernel<<<(A + 255) / 256, 256, 0, stream>>>(anc, reg, ph, pw, out_boxes, A);
    if (clsT)
        transpose_kernel<<<(A + TA - 1) / TA, 256, 0, stream>>>(cls, clsT, A);
    topk_nms_kernel<<<C, NT, 0, stream>>>(clsT, cls, out_boxes, akey, A, C);
    finalize_kernel<<<(A + 255) / 256, 256, 0, stream>>>(akey, out, A);
}

// Round 3
// 180.971 us; speedup vs baseline: 5.6516x; 1.0979x over previous
//
#include <hip/hip_runtime.h>
#include <cstdint>

typedef unsigned long long u64;
typedef unsigned int u32;

#define CLS_T    0.05f
#define TOPK     300
#define NWORDS   5          // ceil(300/64)
#define HBINS    2560
#define KEY_BASE 0x3D000000u
#define NSEG     8
#define SEGCAP   512
#define OPTCAP   1024
#define LOADCAP  3584       // class kernel candidate load cap (4096 - 512 sort region)
#define SORTN    512
#define TTA      128        // anchors per transpose tile

// score -> coarse bin (0 = below threshold; valid bins are >= ~307)
__device__ inline unsigned short score_bin(float s) {
    if (!(s > CLS_T)) return 0;
    u32 k = __float_as_uint(s) - KEY_BASE;
    u32 b = k >> 14;
    if (b > (HBINS - 1)) b = HBINS - 1;
    return (unsigned short)b;
}

// ---------------- decode boxes (+clip) + zero akey ----------------
__global__ void decode_kernel(const float* __restrict__ anc,
                              const float* __restrict__ reg,
                              const int* __restrict__ ph,
                              const int* __restrict__ pw,
                              float* __restrict__ boxes,
                              u64* __restrict__ akey, int A)
{
    int a = blockIdx.x * blockDim.x + threadIdx.x;
    if (a >= A) return;
    akey[a] = 0;
    float x1 = anc[a*4+0], y1 = anc[a*4+1], x2 = anc[a*4+2], y2 = anc[a*4+3];
    float w = x2 - x1, h = y2 - y1;
    float cx = x1 + 0.5f*w, cy = y1 + 0.5f*h;
    float r0 = reg[a*4+0]*0.1f, r1 = reg[a*4+1]*0.1f;
    float r2 = reg[a*4+2]*0.2f, r3 = reg[a*4+3]*0.2f;
    float pcx = cx + r0*w, pcy = cy + r1*h;
    float pw_ = expf(r2)*w, ph_ = expf(r3)*h;
    float W = (float)(*pw), H = (float)(*ph);
    boxes[a*4+0] = fmaxf(pcx - 0.5f*pw_, 0.0f);
    boxes[a*4+1] = fmaxf(pcy - 0.5f*ph_, 0.0f);
    boxes[a*4+2] = fminf(pcx + 0.5f*pw_, W);
    boxes[a*4+3] = fminf(pcy + 0.5f*ph_, H);
}

// ---------------- transpose cls[A][80] -> bin16[80][A] ----------------
__global__ __launch_bounds__(256) void transpose_bin_kernel(
    const float* __restrict__ in, unsigned short* __restrict__ out, int A)
{
    const int C = 80;
    __shared__ unsigned short tile[TTA][81];   // 81: bank-conflict-free strides
    int a0 = blockIdx.x * TTA;
    int rows = A - a0; if (rows > TTA) rows = TTA;

    if (rows == TTA) {
        const float4* in4 = (const float4*)(in + (size_t)a0 * C);
        for (int w = threadIdx.x; w < TTA * C / 4; w += 256) {
            float4 v = in4[w];
            int l = w * 4; int r = l / C; int cc = l - r * C;
            tile[r][cc+0] = score_bin(v.x);
            tile[r][cc+1] = score_bin(v.y);
            tile[r][cc+2] = score_bin(v.z);
            tile[r][cc+3] = score_bin(v.w);
        }
        __syncthreads();
        // write pairs: u32 = two consecutive anchors of one class
        for (int m = threadIdx.x; m < C * (TTA/2); m += 256) {
            int cc = m >> 6;              // / (TTA/2)
            int r2 = (m & (TTA/2 - 1)) << 1;
            u32 wv = (u32)tile[r2][cc] | ((u32)tile[r2+1][cc] << 16);
            *(u32*)(out + (size_t)cc * A + a0 + r2) = wv;
        }
    } else {
        for (int l = threadIdx.x; l < rows * C; l += 256) {
            int r = l / C; int cc = l - r * C;
            tile[r][cc] = score_bin(in[(size_t)(a0 + r) * C + cc]);
        }
        __syncthreads();
        for (int m = threadIdx.x; m < C * rows; m += 256) {
            int cc = m / rows; int r = m - cc * rows;
            out[(size_t)cc * A + a0 + r] = tile[r][cc];
        }
    }
}

// ---------------- per-(class,segment) local top-300 selection ----------------
__global__ __launch_bounds__(256) void seg_select_kernel(
    const unsigned short* __restrict__ clsT16,
    const float* __restrict__ cls,     // [A][C] exact scores for gather
    u64* __restrict__ segcand, u32* __restrict__ segcnt,
    int A, int C, int segsz)
{
    const int blk = blockIdx.x;
    const int c = blk >> 3, seg = blk & 7;
    const int tid = threadIdx.x;
    int a0 = seg * segsz;
    int a1 = a0 + segsz; if (a1 > A) a1 = A;

    __shared__ u32 hist[HBINS];
    __shared__ u32 obuf[OPTCAP];
    __shared__ u32 psum[256];
    __shared__ u32 s_ocnt, s_sel, s_cnt;

    if (a0 >= A) { if (tid == 0) segcnt[blk] = 0; return; }

    const u32 T0BIN = (__float_as_uint(0.97f) - KEY_BASE) >> 14;

    for (int i = tid; i < HBINS; i += 256) hist[i] = 0;
    if (tid == 0) { s_ocnt = 0; s_sel = 0; s_cnt = 0; }
    __syncthreads();

    const unsigned short* row = clsT16 + (size_t)c * A;
    const int n = a1 - a0;
    const int n8 = n >> 3;
    const uint4* p4 = (const uint4*)(row + a0);
    for (int i = tid; i < n8; i += 256) {
        uint4 v = p4[i];
        u32 ws[4] = {v.x, v.y, v.z, v.w};
        #pragma unroll
        for (int q = 0; q < 4; ++q) {
            u32 e0 = ws[q] & 0xFFFFu, e1 = ws[q] >> 16;
            u32 a = (u32)(a0 + i * 8 + q * 2);
            if (e0) {
                atomicAdd(&hist[e0], 1u);
                if (e0 >= T0BIN) { u32 p = atomicAdd(&s_ocnt, 1u); if (p < OPTCAP) obuf[p] = (e0 << 20) | a; }
            }
            if (e1) {
                atomicAdd(&hist[e1], 1u);
                if (e1 >= T0BIN) { u32 p = atomicAdd(&s_ocnt, 1u); if (p < OPTCAP) obuf[p] = (e1 << 20) | (a + 1u); }
            }
        }
    }
    for (int a = a0 + (n8 << 3) + tid; a < a1; a += 256) {
        u32 e = row[a];
        if (e) {
            atomicAdd(&hist[e], 1u);
            if (e >= T0BIN) { u32 p = atomicAdd(&s_ocnt, 1u); if (p < OPTCAP) obuf[p] = (e << 20) | (u32)a; }
        }
    }
    __syncthreads();

    // parallel suffix-scan select: largest bin with suffix >= 300
    {
        int lo = tid * 10, hi2 = lo + 10;
        u32 s = 0;
        for (int d = lo; d < hi2; ++d) s += hist[d];
        psum[tid] = s;
        __syncthreads();
        for (int d = 1; d < 256; d <<= 1) {
            u32 v = (tid + d < 256) ? psum[tid + d] : 0;
            __syncthreads();
            psum[tid] += v;
            __syncthreads();
        }
        u32 base = (tid < 255) ? psum[tid + 1] : 0;
        if (base < TOPK && psum[tid] >= TOPK) {
            u32 run = base;
            for (int d = hi2 - 1; d >= lo; --d) {
                run += hist[d];
                if (run >= TOPK) { s_sel = (u32)d; break; }
            }
        }
        __syncthreads();
    }
    u32 selraw = s_sel;
    u32 sel = selraw < 1 ? 1 : selraw;

    u64* outc = segcand + (size_t)blk * SEGCAP;
    u32 ocnt = s_ocnt;
    bool fast = (ocnt <= OPTCAP) && (selraw >= T0BIN);
    if (fast) {
        for (int i = tid; i < (int)ocnt; i += 256) {
            u32 e = obuf[i];
            if ((e >> 20) >= sel) {
                u32 a = e & 0xFFFFFu;
                u32 bits = __float_as_uint(cls[(size_t)a * C + c]);
                u32 p = atomicAdd(&s_cnt, 1u);
                if (p < SEGCAP) outc[p] = ((u64)bits << 32) | (u32)(~a);
            }
        }
    } else {
        for (int a = a0 + tid; a < a1; a += 256) {
            u32 e = row[a];
            if (e >= sel) {
                u32 bits = __float_as_uint(cls[(size_t)a * C + c]);
                u32 p = atomicAdd(&s_cnt, 1u);
                if (p < SEGCAP) outc[p] = ((u64)bits << 32) | (u32)(~(u32)a);
            }
        }
    }
    __syncthreads();
    if (tid == 0) segcnt[blk] = s_cnt < SEGCAP ? s_cnt : SEGCAP;
}

// ---------------- per-class: merge segments, top-300, NMS, scatter ----------------
__global__ __launch_bounds__(512) void class_nms_kernel(
    const u64* __restrict__ segcand, const u32* __restrict__ segcnt,
    const float* __restrict__ boxes, u64* __restrict__ akey, int A, int C)
{
    const int c = blockIdx.x;
    const int tid = threadIdx.x;

    __shared__ u64 cand[LOADCAP + SORTN];   // [LOADCAP..) = sort buffer
    __shared__ u32 hist[HBINS];
    __shared__ u32 psum[512];
    __shared__ int off[NSEG + 1];
    __shared__ u32 s_sel, s_cnt;
    __shared__ float bx1[TOPK], by1[TOPK], bx2[TOPK], by2[TOPK], bar[TOPK];
    __shared__ u64 iomask[TOPK][NWORDS];
    __shared__ u64 keepm[NWORDS];

    for (int i = tid; i < HBINS; i += 512) hist[i] = 0;
    if (tid == 0) {
        int o = 0;
        for (int s2 = 0; s2 < NSEG; ++s2) { off[s2] = o; o += (int)segcnt[c * NSEG + s2]; }
        off[NSEG] = o;
        s_sel = 0; s_cnt = 0;
    }
    __syncthreads();
    int ntot = off[NSEG]; if (ntot > LOADCAP) ntot = LOADCAP;

    for (int s2 = 0; s2 < NSEG; ++s2) {
        int base = off[s2], cnt = off[s2 + 1] - off[s2];
        const u64* src = segcand + (size_t)(c * NSEG + s2) * SEGCAP;
        for (int i = tid; i < cnt; i += 512) {
            int d = base + i;
            if (d < LOADCAP) cand[d] = src[i];
        }
    }
    __syncthreads();

    for (int i = tid; i < ntot; i += 512) {
        u32 k = (u32)(cand[i] >> 32) - KEY_BASE;
        u32 b = k >> 14; if (b > (HBINS - 1)) b = HBINS - 1;
        atomicAdd(&hist[b], 1u);
    }
    __syncthreads();

    // parallel suffix-scan select for top-300
    {
        int lo = tid * 5, hi2 = lo + 5;
        u32 s = 0;
        for (int d = lo; d < hi2; ++d) s += hist[d];
        psum[tid] = s;
        __syncthreads();
        for (int d = 1; d < 512; d <<= 1) {
            u32 v = (tid + d < 512) ? psum[tid + d] : 0;
            __syncthreads();
            psum[tid] += v;
            __syncthreads();
        }
        u32 base = (tid < 511) ? psum[tid + 1] : 0;
        if (base < TOPK && psum[tid] >= TOPK) {
            u32 run = base;
            for (int d = hi2 - 1; d >= lo; --d) {
                run += hist[d];
                if (run >= TOPK) { s_sel = (u32)d; break; }
            }
        }
        __syncthreads();
    }
    const u32 sel = s_sel;

    u64* sbuf = &cand[LOADCAP];
    for (int i = tid; i < ntot; i += 512) {
        u64 key = cand[i];
        u32 k = (u32)(key >> 32) - KEY_BASE;
        u32 b = k >> 14; if (b > (HBINS - 1)) b = HBINS - 1;
        if (b >= sel) {
            u32 p = atomicAdd(&s_cnt, 1u);
            if (p < SORTN) sbuf[p] = key;
        }
    }
    __syncthreads();
    const int nsort = (int)(s_cnt < SORTN ? s_cnt : SORTN);
    for (int i = nsort + tid; i < SORTN; i += 512) sbuf[i] = 0;
    __syncthreads();

    // bitonic sort descending, 512 threads / 512 elements
    for (u32 kk = 2; kk <= SORTN; kk <<= 1) {
        for (u32 j = kk >> 1; j > 0; j >>= 1) {
            u32 i = tid, l = tid ^ j;
            if (l > i) {
                u64 av = sbuf[i], bv = sbuf[l];
                bool up = ((i & kk) == 0);
                if ((up && av < bv) || (!up && av > bv)) { sbuf[i] = bv; sbuf[l] = av; }
            }
            __syncthreads();
        }
    }
    const int T = nsort < TOPK ? nsort : TOPK;

    // candidate boxes
    for (int i = tid; i < T; i += 512) {
        u32 a = ~(u32)(sbuf[i] & 0xFFFFFFFFull);
        float x1 = boxes[(size_t)a*4+0], y1 = boxes[(size_t)a*4+1];
        float x2 = boxes[(size_t)a*4+2], y2 = boxes[(size_t)a*4+3];
        bx1[i] = x1; by1[i] = y1; bx2[i] = x2; by2[i] = y2;
        bar[i] = fmaxf(x2 - x1, 0.0f) * fmaxf(y2 - y1, 0.0f);
    }
    __syncthreads();

    // pairwise IoU masks
    for (int i = tid; i < T; i += 512) {
        u64 m[NWORDS] = {0,0,0,0,0};
        float x1 = bx1[i], y1 = by1[i], x2 = bx2[i], y2 = by2[i], ai = bar[i];
        for (int j = i + 1; j < T; ++j) {
            float iw = fmaxf(fminf(x2, bx2[j]) - fmaxf(x1, bx1[j]), 0.0f);
            float ih = fmaxf(fminf(y2, by2[j]) - fmaxf(y1, by1[j]), 0.0f);
            float inter = iw * ih;
            float uni = ((ai + bar[j]) - inter) + 1e-8f;
            if (inter / uni > 0.5f) m[j >> 6] |= 1ull << (j & 63);
        }
        for (int k2 = 0; k2 < NWORDS; ++k2) iomask[i][k2] = m[k2];
    }
    __syncthreads();

    // greedy suppression, leader-skip (iterate kept boxes only)
    if (tid == 0) {
        u64 sup[NWORDS] = {0,0,0,0,0};
        u64 kp [NWORDS] = {0,0,0,0,0};
        int i = 0;
        while (i < T) {
            kp[i >> 6] |= 1ull << (i & 63);
            #pragma unroll
            for (int k2 = 0; k2 < NWORDS; ++k2) sup[k2] |= iomask[i][k2];
            sup[i >> 6] |= 1ull << (i & 63);
            int ni = T;
            for (int k2 = i >> 6; k2 < NWORDS; ++k2) {
                u64 m = ~sup[k2];
                if (k2 == (i >> 6)) m &= ~((2ull << (i & 63)) - 1ull);
                if (m) { ni = (k2 << 6) + __ffsll((unsigned long long)m) - 1; break; }
            }
            i = ni;
        }
        for (int k2 = 0; k2 < NWORDS; ++k2) keepm[k2] = kp[k2];
    }
    __syncthreads();

    // scatter kept: per-anchor max via u64 atomicMax
    for (int i = tid; i < T; i += 512) {
        if ((keepm[i >> 6] >> (i & 63)) & 1ull) {
            u64 key = sbuf[i];
            u32 a = ~(u32)(key & 0xFFFFFFFFull);
            u32 sbits = (u32)(key >> 32);
            u64 outk = ((u64)sbits << 32) | (u32)(255 - c);
            atomicMax(&akey[a], outk);
        }
    }
}

// ---------------- finalize ----------------
__global__ void finalize_kernel(const u64* __restrict__ akey,
                                float* __restrict__ out, int A)
{
    int a = blockIdx.x * blockDim.x + threadIdx.x;
    if (a >= A) return;
    float* scores = out;
    float* labels = out + A;
    float* boxes  = out + (size_t)2 * A;
    u64 k = akey[a];
    if (k) {
        scores[a] = __uint_as_float((u32)(k >> 32));
        labels[a] = (float)(int)(255u - (u32)(k & 0xFFFFFFFFull));
    } else {
        scores[a] = 0.0f;
        labels[a] = -1.0f;
        boxes[(size_t)a*4+0] = 0.0f;
        boxes[(size_t)a*4+1] = 0.0f;
        boxes[(size_t)a*4+2] = 0.0f;
        boxes[(size_t)a*4+3] = 0.0f;
    }
}

// ---------------- fallback (generic C / small ws): round-1 proven kernel ----------------
#define FB_CAP 1024
__global__ __launch_bounds__(256) void fb_topk_nms_kernel(
    const float* __restrict__ cls,
    const float* __restrict__ boxes,
    u64* __restrict__ akey,
    int A, int C)
{
    const int c   = blockIdx.x;
    const int tid = threadIdx.x;

    __shared__ u32 hist[HBINS];
    __shared__ u64 cand[FB_CAP];
    __shared__ float bx1[TOPK], by1[TOPK], bx2[TOPK], by2[TOPK], bar[TOPK];
    __shared__ u64 iomask[TOPK][NWORDS];
    __shared__ u64 keepm[NWORDS];
    __shared__ u32 s_sel1, s_sel2, s_rem, s_cnt;

    for (int i = tid; i < HBINS; i += 256) hist[i] = 0;
    __syncthreads();
    for (int a = tid; a < A; a += 256) {
        float s = cls[(size_t)a * C + c];
        if (s > CLS_T) {
            u32 k = __float_as_uint(s) - KEY_BASE;
            u32 b = k >> 14; if (b >= HBINS) b = HBINS - 1;
            atomicAdd(&hist[b], 1u);
        }
    }
    __syncthreads();
    if (tid == 0) {
        u32 cum = 0; int sel = 0;
        for (int d = HBINS - 1; d >= 0; --d) {
            u32 nc = cum + hist[d];
            if (nc >= TOPK) { sel = d; break; }
            cum = nc;
        }
        s_sel1 = (u32)sel; s_rem = TOPK - cum;
    }
    __syncthreads();
    const u32 sel1 = s_sel1;

    for (int i = tid; i < 256; i += 256) hist[i] = 0;
    __syncthreads();
    for (int a = tid; a < A; a += 256) {
        float s = cls[(size_t)a * C + c];
        if (s > CLS_T) {
            u32 k = __float_as_uint(s) - KEY_BASE;
            u32 b = k >> 14; if (b >= HBINS) b = HBINS - 1;
            if (b == sel1) atomicAdd(&hist[(k >> 6) & 0xFF], 1u);
        }
    }
    __syncthreads();
    if (tid == 0) {
        u32 rem = s_rem, cum = 0; int sel = 0;
        for (int d = 255; d >= 0; --d) {
            u32 nc = cum + hist[d];
            if (nc >= rem) { sel = d; break; }
            cum = nc;
        }
        s_sel2 = (u32)sel; s_cnt = 0;
    }
    __syncthreads();
    const u32 thresh = (sel1 << 14) | (s_sel2 << 6);

    for (int a = tid; a < A; a += 256) {
        float s = cls[(size_t)a * C + c];
        if (s > CLS_T) {
            u32 bits = __float_as_uint(s);
            u32 k = bits - KEY_BASE;
            if (k >= thresh) {
                u32 pos = atomicAdd(&s_cnt, 1u);
                if (pos < FB_CAP) cand[pos] = ((u64)bits << 32) | (u32)(~(u32)a);
            }
        }
    }
    __syncthreads();
    const u32 total = s_cnt < FB_CAP ? s_cnt : FB_CAP;
    for (int i = tid; i < FB_CAP; i += 256)
        if (i >= (int)total) cand[i] = 0;
    __syncthreads();

    for (u32 kk = 2; kk <= FB_CAP; kk <<= 1) {
        for (u32 j = kk >> 1; j > 0; j >>= 1) {
            for (u32 i = tid; i < FB_CAP; i += 256) {
                u32 l = i ^ j;
                if (l > i) {
                    u64 av = cand[i], bv = cand[l];
                    bool up = ((i & kk) == 0);
                    if ((up && av < bv) || (!up && av > bv)) { cand[i] = bv; cand[l] = av; }
                }
            }
            __syncthreads();
        }
    }
    const int T = (int)(total < TOPK ? total : TOPK);

    for (int i = tid; i < T; i += 256) {
        u32 a = ~(u32)(cand[i] & 0xFFFFFFFFull);
        float x1 = boxes[(size_t)a*4+0], y1 = boxes[(size_t)a*4+1];
        float x2 = boxes[(size_t)a*4+2], y2 = boxes[(size_t)a*4+3];
        bx1[i] = x1; by1[i] = y1; bx2[i] = x2; by2[i] = y2;
        bar[i] = fmaxf(x2 - x1, 0.0f) * fmaxf(y2 - y1, 0.0f);
    }
    __syncthreads();

    for (int i = tid; i < T; i += 256) {
        u64 m[NWORDS] = {0,0,0,0,0};
        float x1 = bx1[i], y1 = by1[i], x2 = bx2[i], y2 = by2[i], ai = bar[i];
        for (int j = i + 1; j < T; ++j) {
            float iw = fmaxf(fminf(x2, bx2[j]) - fmaxf(x1, bx1[j]), 0.0f);
            float ih = fmaxf(fminf(y2, by2[j]) - fmaxf(y1, by1[j]), 0.0f);
            float inter = iw * ih;
            float uni = ((ai + bar[j]) - inter) + 1e-8f;
            if (inter / uni > 0.5f) m[j >> 6] |= 1ull << (j & 63);
        }
        for (int k2 = 0; k2 < NWORDS; ++k2) iomask[i][k2] = m[k2];
    }
    __syncthreads();

    if (tid == 0) {
        u64 sup[NWORDS] = {0,0,0,0,0};
        u64 kp [NWORDS] = {0,0,0,0,0};
        for (int i = 0; i < T; ++i) {
            if (!((sup[i >> 6] >> (i & 63)) & 1ull)) {
                kp[i >> 6] |= 1ull << (i & 63);
                for (int k2 = 0; k2 < NWORDS; ++k2) sup[k2] |= iomask[i][k2];
            }
        }
        for (int k2 = 0; k2 < NWORDS; ++k2) keepm[k2] = kp[k2];
    }
    __syncthreads();

    for (int i = tid; i < T; i += 256) {
        if ((keepm[i >> 6] >> (i & 63)) & 1ull) {
            u64 key = cand[i];
            u32 a = ~(u32)(key & 0xFFFFFFFFull);
            u32 sbits = (u32)(key >> 32);
            u64 outk = ((u64)sbits << 32) | (u32)(255 - c);
            atomicMax(&akey[a], outk);
        }
    }
}

extern "C" void kernel_launch(void* const* d_in, const int* in_sizes, int n_in,
                              void* d_out, int out_size, void* d_ws, size_t ws_size,
                              hipStream_t stream) {
    const float* cls = (const float*)d_in[0];
    const float* reg = (const float*)d_in[1];
    const float* anc = (const float*)d_in[2];
    const int*   ph  = (const int*)d_in[3];
    const int*   pw  = (const int*)d_in[4];

    int A = in_sizes[2] / 4;
    int C = in_sizes[0] / A;

    float* out       = (float*)d_out;
    float* out_boxes = out + (size_t)2 * A;

    // workspace layout
    size_t akey_bytes = (size_t)A * sizeof(u64);
    size_t off_cand   = (akey_bytes + 255) & ~(size_t)255;
    size_t cand_bytes = (size_t)C * NSEG * SEGCAP * sizeof(u64);
    size_t off_cnt    = (off_cand + cand_bytes + 255) & ~(size_t)255;
    size_t cnt_bytes  = (size_t)C * NSEG * sizeof(u32);
    size_t off_t16    = (off_cnt + cnt_bytes + 255) & ~(size_t)255;
    size_t t16_bytes  = (size_t)A * C * sizeof(unsigned short);
    size_t need       = off_t16 + t16_bytes;

    u64* akey = (u64*)d_ws;

    decode_kernel<<<(A + 255) / 256, 256, 0, stream>>>(anc, reg, ph, pw, out_boxes, akey, A);

    bool fastpath = (C == 80) && (A < (1 << 20)) && (ws_size >= need);
    if (fastpath) {
        u64* segcand = (u64*)((char*)d_ws + off_cand);
        u32* segcnt  = (u32*)((char*)d_ws + off_cnt);
        unsigned short* clsT16 = (unsigned short*)((char*)d_ws + off_t16);
        int segsz = (((A + NSEG - 1) / NSEG) + 7) & ~7;

        transpose_bin_kernel<<<(A + TTA - 1) / TTA, 256, 0, stream>>>(cls, clsT16, A);
        seg_select_kernel<<<C * NSEG, 256, 0, stream>>>(clsT16, cls, segcand, segcnt, A, C, segsz);
        class_nms_kernel<<<C, 512, 0, stream>>>(segcand, segcnt, out_boxes, akey, A, C);
    } else {
        fb_topk_nms_kernel<<<C, 256, 0, stream>>>(cls, out_boxes, akey, A, C);
    }

    finalize_kernel<<<(A + 255) / 256, 256, 0, stream>>>(akey, out, A);
}